// Round 1
// baseline (581.953 us; speedup 1.0000x reference)
//
#include <hip/hip_runtime.h>
#include <hip/hip_bf16.h>

#define DIM  1024
#define RANK 32
#define BATCH 4
#define SEQ  4096

typedef short bf16x8 __attribute__((ext_vector_type(8)));          // 8 bf16 (4 VGPRs) MFMA A/B frag
typedef float f32x4 __attribute__((ext_vector_type(4)));           // MFMA C/D frag
typedef unsigned short ushort4v __attribute__((ext_vector_type(4)));
typedef unsigned short ushort8v __attribute__((ext_vector_type(8)));

__device__ inline unsigned short f2bf(float f) {
    union { float f; unsigned int u; } v; v.f = f;
    return (unsigned short)((v.u + 0x7FFFu + ((v.u >> 16) & 1u)) >> 16);  // RNE
}

// ---------------- K0: pack Q,K (fp32 32x1024 each) -> wqk bf16 (64x1024) ----------------
__global__ __launch_bounds__(256) void k_cvt_qk(const float* __restrict__ Q,
                                                const float* __restrict__ K,
                                                unsigned short* __restrict__ wqk) {
    int i = blockIdx.x * 256 + threadIdx.x;        // 65536 total
    int row = i >> 10, col = i & 1023;
    float v = (row < RANK) ? Q[row * DIM + col] : K[(row - RANK) * DIM + col];
    wqk[i] = f2bf(v);
}

// ---------------- K1: tiled transpose + fp32->bf16: out[c][r] = in[r][c] ----------------
// in: R x C fp32, out: C x R bf16. grid (C/64, R/64, nbatch)
__global__ __launch_bounds__(256) void k_transpose_cvt(const float* __restrict__ in,
                                                       unsigned short* __restrict__ out,
                                                       int R, int C,
                                                       int inBatchStride, int outBatchStride) {
    __shared__ float tile[64][65];   // +1 pad breaks bank conflicts on transposed read
    const int tid = threadIdx.x;
    const int c0 = blockIdx.x * 64, r0 = blockIdx.y * 64;
    const float* src = in + (size_t)blockIdx.z * (size_t)inBatchStride;
    unsigned short* dst = out + (size_t)blockIdx.z * (size_t)outBatchStride;
    {
        int c = (tid & 15) * 4;
#pragma unroll
        for (int i = 0; i < 4; ++i) {
            int r = (tid >> 4) + i * 16;
            f32x4 v = *(const f32x4*)(src + (size_t)(r0 + r) * C + c0 + c);
            tile[r][c + 0] = v[0]; tile[r][c + 1] = v[1];
            tile[r][c + 2] = v[2]; tile[r][c + 3] = v[3];
        }
    }
    __syncthreads();
    {
        int r = (tid & 15) * 4;
#pragma unroll
        for (int i = 0; i < 4; ++i) {
            int c = (tid >> 4) + i * 16;
            ushort4v o;
            o[0] = f2bf(tile[r + 0][c]); o[1] = f2bf(tile[r + 1][c]);
            o[2] = f2bf(tile[r + 2][c]); o[3] = f2bf(tile[r + 3][c]);
            *(ushort4v*)(dst + (size_t)(c0 + c) * R + r0 + r) = o;
        }
    }
}

// ---------------- K2: xqk[t][0:32]=x@Q^T, [32:64]=x@K^T (bf16 out) ----------------
// M=B*S=16384, N=64, K=1024. Block: 128 rows. grid(128)
__global__ __launch_bounds__(256) void k_proj(const float* __restrict__ x,
                                              const unsigned short* __restrict__ wqk,
                                              unsigned short* __restrict__ xqk) {
    __shared__ unsigned short a_lds[128 * 40];   // 128 rows x 32 k, pad->40
    __shared__ unsigned short w_lds[64 * 40];
    const int tid = threadIdx.x;
    const int wave = tid >> 6, lane = tid & 63, l15 = lane & 15, quad = lane >> 4;
    const int rowbase = blockIdx.x * 128;

    f32x4 acc[2][4];
#pragma unroll
    for (int qi = 0; qi < 2; ++qi)
#pragma unroll
        for (int ni = 0; ni < 4; ++ni) acc[qi][ni] = (f32x4){0.f, 0.f, 0.f, 0.f};

    for (int k0 = 0; k0 < DIM; k0 += 32) {
        {   // stage A (fp32 -> bf16 on the fly): 128 x 32
            int row = tid >> 1, koff = (tid & 1) * 16;
            const float* src = x + (size_t)(rowbase + row) * DIM + k0 + koff;
            ushort8v t0, t1;
#pragma unroll
            for (int j = 0; j < 8; j += 4) {
                f32x4 v = *(const f32x4*)(src + j);
                t0[j + 0] = f2bf(v[0]); t0[j + 1] = f2bf(v[1]);
                t0[j + 2] = f2bf(v[2]); t0[j + 3] = f2bf(v[3]);
            }
#pragma unroll
            for (int j = 0; j < 8; j += 4) {
                f32x4 v = *(const f32x4*)(src + 8 + j);
                t1[j + 0] = f2bf(v[0]); t1[j + 1] = f2bf(v[1]);
                t1[j + 2] = f2bf(v[2]); t1[j + 3] = f2bf(v[3]);
            }
            *(ushort8v*)&a_lds[row * 40 + koff] = t0;
            *(ushort8v*)&a_lds[row * 40 + koff + 8] = t1;
        }
        if (tid < 128) {   // stage W: 64 x 32 bf16
            int row = tid >> 1, koff = (tid & 1) * 16;
            ushort8v v0 = *(const ushort8v*)(wqk + (size_t)row * DIM + k0 + koff);
            ushort8v v1 = *(const ushort8v*)(wqk + (size_t)row * DIM + k0 + koff + 8);
            *(ushort8v*)&w_lds[row * 40 + koff] = v0;
            *(ushort8v*)&w_lds[row * 40 + koff + 8] = v1;
        }
        __syncthreads();
        bf16x8 a0 = *(const bf16x8*)&a_lds[(wave * 32 + l15) * 40 + quad * 8];
        bf16x8 a1 = *(const bf16x8*)&a_lds[(wave * 32 + 16 + l15) * 40 + quad * 8];
#pragma unroll
        for (int ni = 0; ni < 4; ++ni) {
            bf16x8 w = *(const bf16x8*)&w_lds[(ni * 16 + l15) * 40 + quad * 8];
            acc[0][ni] = __builtin_amdgcn_mfma_f32_16x16x32_bf16(a0, w, acc[0][ni], 0, 0, 0);
            acc[1][ni] = __builtin_amdgcn_mfma_f32_16x16x32_bf16(a1, w, acc[1][ni], 0, 0, 0);
        }
        __syncthreads();
    }
#pragma unroll
    for (int qi = 0; qi < 2; ++qi)
#pragma unroll
        for (int ni = 0; ni < 4; ++ni)
#pragma unroll
            for (int r = 0; r < 4; ++r) {
                int grow = rowbase + wave * 32 + qi * 16 + quad * 4 + r;
                xqk[(size_t)grow * 64 + ni * 16 + l15] = f2bf(acc[qi][ni][r]);
            }
}

// ---------------- K3: attention. block = 64 q x 128 d chunk; loop 64-key blocks --------
// No max-subtraction needed: |score/32| <= ~2.5 (rank-32, Cauchy-Schwarz bound).
__global__ __launch_bounds__(256) void k_attn(const unsigned short* __restrict__ xqk,
                                              const unsigned short* __restrict__ xt,
                                              unsigned short* __restrict__ ctx) {
    __shared__ unsigned short xq_lds[64 * 40];
    __shared__ unsigned short xk_lds[64 * 40];
    __shared__ unsigned short p_lds[64 * 72];     // P: 64 q x 64 keys (pad 72)
    __shared__ unsigned short xt_lds[128 * 72];   // 128 d x 64 keys

    const int tid = threadIdx.x;
    const int wave = tid >> 6, lane = tid & 63, l15 = lane & 15, quad = lane >> 4;
    const int dbase = blockIdx.x * 128;
    const int qbase = blockIdx.y * 64;
    const int b = blockIdx.z;

    {   // stage xq tile once: 64 q rows x 32 rank (cols 0..31 of xqk)
        int row = tid >> 2, koff = (tid & 3) * 8;
        ushort8v v = *(const ushort8v*)(xqk + (size_t)(b * SEQ + qbase + row) * 64 + koff);
        *(ushort8v*)&xq_lds[row * 40 + koff] = v;
    }
    __syncthreads();
    bf16x8 aq = *(const bf16x8*)&xq_lds[(wave * 16 + l15) * 40 + quad * 8];

    f32x4 acc[8];
#pragma unroll
    for (int i = 0; i < 8; ++i) acc[i] = (f32x4){0.f, 0.f, 0.f, 0.f};
    float denacc[4] = {0.f, 0.f, 0.f, 0.f};
    const f32x4 zero = (f32x4){0.f, 0.f, 0.f, 0.f};
    const float SC = 0.045084220027779984f;   // 1/(32*ln2): exp(s/32) = exp2(s*SC)

    for (int kb = 0; kb < SEQ / 64; ++kb) {
        const int kkey = kb * 64;
        {   // stage xk block: 64 keys x 32 (cols 32..63 of xqk)
            int row = tid >> 2, koff = (tid & 3) * 8;
            ushort8v v = *(const ushort8v*)(xqk + (size_t)(b * SEQ + kkey + row) * 64 + 32 + koff);
            *(ushort8v*)&xk_lds[row * 40 + koff] = v;
        }
        {   // stage x_t tile: 128 d x 64 keys
#pragma unroll
            for (int i = 0; i < 4; ++i) {
                int idx = i * 256 + tid;
                int drow = idx >> 3, kcol = (idx & 7) * 8;
                ushort8v v = *(const ushort8v*)(xt + (size_t)(b * DIM + dbase + drow) * SEQ + kkey + kcol);
                *(ushort8v*)&xt_lds[drow * 72 + kcol] = v;
            }
        }
        __syncthreads();

        // scores: wave's 16 q rows x 64 keys (4 MFMAs, K=32=RANK exactly)
#pragma unroll
        for (int kt = 0; kt < 4; ++kt) {
            bf16x8 bk = *(const bf16x8*)&xk_lds[(kt * 16 + l15) * 40 + quad * 8];
            f32x4 s = __builtin_amdgcn_mfma_f32_16x16x32_bf16(aq, bk, zero, 0, 0, 0);
#pragma unroll
            for (int r = 0; r < 4; ++r) {
                float e = exp2f(s[r] * SC);
                denacc[r] += e;
                p_lds[(wave * 16 + quad * 4 + r) * 72 + kt * 16 + l15] = f2bf(e);
            }
        }
        __syncthreads();

        // PV: acc[16 q x 128 d] += P(16x64) @ xt(64x128)^T-in-B-layout
#pragma unroll
        for (int ks = 0; ks < 2; ++ks) {
            bf16x8 ap = *(const bf16x8*)&p_lds[(wave * 16 + l15) * 72 + ks * 32 + quad * 8];
#pragma unroll
            for (int dt = 0; dt < 8; ++dt) {
                bf16x8 bx = *(const bf16x8*)&xt_lds[(dt * 16 + l15) * 72 + ks * 32 + quad * 8];
                acc[dt] = __builtin_amdgcn_mfma_f32_16x16x32_bf16(ap, bx, acc[dt], 0, 0, 0);
            }
        }
        __syncthreads();
    }

    // denominator: sum per q-row over its 16 column-lanes (xor butterfly within quad group)
    float rden[4];
#pragma unroll
    for (int r = 0; r < 4; ++r) {
        float d = denacc[r];
        d += __shfl_xor(d, 1);
        d += __shfl_xor(d, 2);
        d += __shfl_xor(d, 4);
        d += __shfl_xor(d, 8);
        rden[r] = 1.0f / d;
    }
#pragma unroll
    for (int dt = 0; dt < 8; ++dt)
#pragma unroll
        for (int r = 0; r < 4; ++r) {
            int grow = b * SEQ + qbase + wave * 16 + quad * 4 + r;
            int gcol = dbase + dt * 16 + l15;
            ctx[(size_t)grow * DIM + gcol] = f2bf(acc[dt][r] * rden[r]);
        }
}

// ---------------- K4: out = ctx @ VO  (via VO_t rows). M=16384,N=1024,K=1024 ----------
__global__ __launch_bounds__(256) void k_out(const unsigned short* __restrict__ ctx,
                                             const unsigned short* __restrict__ vot,
                                             float* __restrict__ out) {
    __shared__ unsigned short a_lds[128 * 40];
    __shared__ unsigned short b_lds[128 * 40];
    const int tid = threadIdx.x;
    const int wave = tid >> 6, lane = tid & 63, l15 = lane & 15, quad = lane >> 4;
    const int nbase = blockIdx.x * 128;
    const int rowbase = blockIdx.y * 128;

    f32x4 acc[2][8];
#pragma unroll
    for (int qi = 0; qi < 2; ++qi)
#pragma unroll
        for (int nt = 0; nt < 8; ++nt) acc[qi][nt] = (f32x4){0.f, 0.f, 0.f, 0.f};

    for (int k0 = 0; k0 < DIM; k0 += 32) {
        int row = tid >> 1, koff = (tid & 1) * 16;
        {   // A: 128 rows x 32 of ctx
            ushort8v v0 = *(const ushort8v*)(ctx + (size_t)(rowbase + row) * DIM + k0 + koff);
            ushort8v v1 = *(const ushort8v*)(ctx + (size_t)(rowbase + row) * DIM + k0 + koff + 8);
            *(ushort8v*)&a_lds[row * 40 + koff] = v0;
            *(ushort8v*)&a_lds[row * 40 + koff + 8] = v1;
        }
        {   // B: 128 n-rows x 32 of VO_t
            ushort8v v0 = *(const ushort8v*)(vot + (size_t)(nbase + row) * DIM + k0 + koff);
            ushort8v v1 = *(const ushort8v*)(vot + (size_t)(nbase + row) * DIM + k0 + koff + 8);
            *(ushort8v*)&b_lds[row * 40 + koff] = v0;
            *(ushort8v*)&b_lds[row * 40 + koff + 8] = v1;
        }
        __syncthreads();
        bf16x8 a0 = *(const bf16x8*)&a_lds[(wave * 32 + l15) * 40 + quad * 8];
        bf16x8 a1 = *(const bf16x8*)&a_lds[(wave * 32 + 16 + l15) * 40 + quad * 8];
#pragma unroll
        for (int nt = 0; nt < 8; ++nt) {
            bf16x8 bn = *(const bf16x8*)&b_lds[(nt * 16 + l15) * 40 + quad * 8];
            acc[0][nt] = __builtin_amdgcn_mfma_f32_16x16x32_bf16(a0, bn, acc[0][nt], 0, 0, 0);
            acc[1][nt] = __builtin_amdgcn_mfma_f32_16x16x32_bf16(a1, bn, acc[1][nt], 0, 0, 0);
        }
        __syncthreads();
    }
#pragma unroll
    for (int qi = 0; qi < 2; ++qi)
#pragma unroll
        for (int nt = 0; nt < 8; ++nt)
#pragma unroll
            for (int r = 0; r < 4; ++r) {
                int grow = rowbase + wave * 32 + qi * 16 + quad * 4 + r;
                out[(size_t)grow * DIM + nbase + nt * 16 + l15] = acc[qi][nt][r];
            }
}

extern "C" void kernel_launch(void* const* d_in, const int* in_sizes, int n_in,
                              void* d_out, int out_size, void* d_ws, size_t ws_size,
                              hipStream_t stream) {
    const float* x  = (const float*)d_in[0];
    const float* Q  = (const float*)d_in[1];
    const float* K  = (const float*)d_in[2];
    const float* VO = (const float*)d_in[3];
    float* out = (float*)d_out;

    char* ws = (char*)d_ws;
    // workspace layout (bytes), all 256-aligned; total ~68.2 MB
    unsigned short* wqk = (unsigned short*)(ws + 0);          // 64x1024 bf16      = 128 KB
    unsigned short* vot = (unsigned short*)(ws + 131072);     // 1024x1024 bf16    = 2 MB
    unsigned short* xqk = (unsigned short*)(ws + 2228224);    // 16384x64 bf16     = 2 MB
    unsigned short* xt  = (unsigned short*)(ws + 4325376);    // 4x1024x4096 bf16  = 32 MB
    unsigned short* ctx = (unsigned short*)(ws + 37879808);   // 16384x1024 bf16   = 32 MB

    k_cvt_qk<<<256, 256, 0, stream>>>(Q, K, wqk);
    // VO (1024x1024) -> VO_t[e][d]
    k_transpose_cvt<<<dim3(16, 16, 1), 256, 0, stream>>>(VO, vot, 1024, 1024, 0, 0);
    // x[b] (4096x1024) -> x_t[b] (1024x4096)
    k_transpose_cvt<<<dim3(16, 64, BATCH), 256, 0, stream>>>(x, xt, SEQ, DIM, SEQ * DIM, DIM * SEQ);
    k_proj<<<128, 256, 0, stream>>>(x, wqk, xqk);
    k_attn<<<dim3(DIM / 128, SEQ / 64, BATCH), 256, 0, stream>>>(xqk, xt, ctx);
    k_out<<<dim3(DIM / 128, 16384 / 128, 1), 256, 0, stream>>>(ctx, vot, out);
}

// Round 2
// 469.690 us; speedup vs baseline: 1.2390x; 1.2390x over previous
//
#include <hip/hip_runtime.h>
#include <hip/hip_bf16.h>

#define DIM  1024
#define RANK 32
#define BATCH 4
#define SEQ  4096

typedef short bf16x8 __attribute__((ext_vector_type(8)));          // 8 bf16 (4 VGPRs) MFMA A/B frag
typedef float f32x4 __attribute__((ext_vector_type(4)));           // 16x16 MFMA C/D frag
typedef float f32x16 __attribute__((ext_vector_type(16)));         // 32x32 MFMA C/D frag
typedef unsigned short ushort4v __attribute__((ext_vector_type(4)));
typedef unsigned short ushort8v __attribute__((ext_vector_type(8)));
typedef unsigned int uint2v __attribute__((ext_vector_type(2)));

__device__ inline unsigned short f2bf(float f) {
    union { float f; unsigned int u; } v; v.f = f;
    return (unsigned short)((v.u + 0x7FFFu + ((v.u >> 16) & 1u)) >> 16);  // RNE
}

__device__ inline unsigned int pk_bf16(float a, float b) {
    __hip_bfloat162 h = __float22bfloat162_rn(make_float2(a, b));
    unsigned int u; __builtin_memcpy(&u, &h, 4);
    return u;
}

// ---------------- K0: pack Q,K (fp32 32x1024 each) -> wqk bf16 (64x1024) ----------------
__global__ __launch_bounds__(256) void k_cvt_qk(const float* __restrict__ Q,
                                                const float* __restrict__ K,
                                                unsigned short* __restrict__ wqk) {
    int i = blockIdx.x * 256 + threadIdx.x;        // 65536 total
    int row = i >> 10, col = i & 1023;
    float v = (row < RANK) ? Q[row * DIM + col] : K[(row - RANK) * DIM + col];
    wqk[i] = f2bf(v);
}

// ---------------- K1: tiled transpose + fp32->bf16: out[c][r] = in[r][c] ----------------
__global__ __launch_bounds__(256) void k_transpose_cvt(const float* __restrict__ in,
                                                       unsigned short* __restrict__ out,
                                                       int R, int C,
                                                       int inBatchStride, int outBatchStride) {
    __shared__ float tile[64][65];
    const int tid = threadIdx.x;
    const int c0 = blockIdx.x * 64, r0 = blockIdx.y * 64;
    const float* src = in + (size_t)blockIdx.z * (size_t)inBatchStride;
    unsigned short* dst = out + (size_t)blockIdx.z * (size_t)outBatchStride;
    {
        int c = (tid & 15) * 4;
#pragma unroll
        for (int i = 0; i < 4; ++i) {
            int r = (tid >> 4) + i * 16;
            f32x4 v = *(const f32x4*)(src + (size_t)(r0 + r) * C + c0 + c);
            tile[r][c + 0] = v[0]; tile[r][c + 1] = v[1];
            tile[r][c + 2] = v[2]; tile[r][c + 3] = v[3];
        }
    }
    __syncthreads();
    {
        int r = (tid & 15) * 4;
#pragma unroll
        for (int i = 0; i < 4; ++i) {
            int c = (tid >> 4) + i * 16;
            ushort4v o;
            o[0] = f2bf(tile[r + 0][c]); o[1] = f2bf(tile[r + 1][c]);
            o[2] = f2bf(tile[r + 2][c]); o[3] = f2bf(tile[r + 3][c]);
            *(ushort4v*)(dst + (size_t)(c0 + c) * R + r0 + r) = o;
        }
    }
}

// ---------------- K2: xqk[t][0:32]=x@Q^T, [32:64]=x@K^T (bf16 out) ----------------
__global__ __launch_bounds__(256) void k_proj(const float* __restrict__ x,
                                              const unsigned short* __restrict__ wqk,
                                              unsigned short* __restrict__ xqk) {
    __shared__ unsigned short a_lds[128 * 40];
    __shared__ unsigned short w_lds[64 * 40];
    const int tid = threadIdx.x;
    const int wave = tid >> 6, lane = tid & 63, l15 = lane & 15, quad = lane >> 4;
    const int rowbase = blockIdx.x * 128;

    f32x4 acc[2][4];
#pragma unroll
    for (int qi = 0; qi < 2; ++qi)
#pragma unroll
        for (int ni = 0; ni < 4; ++ni) acc[qi][ni] = (f32x4){0.f, 0.f, 0.f, 0.f};

    for (int k0 = 0; k0 < DIM; k0 += 32) {
        {
            int row = tid >> 1, koff = (tid & 1) * 16;
            const float* src = x + (size_t)(rowbase + row) * DIM + k0 + koff;
            ushort8v t0, t1;
#pragma unroll
            for (int j = 0; j < 8; j += 4) {
                f32x4 v = *(const f32x4*)(src + j);
                t0[j + 0] = f2bf(v[0]); t0[j + 1] = f2bf(v[1]);
                t0[j + 2] = f2bf(v[2]); t0[j + 3] = f2bf(v[3]);
            }
#pragma unroll
            for (int j = 0; j < 8; j += 4) {
                f32x4 v = *(const f32x4*)(src + 8 + j);
                t1[j + 0] = f2bf(v[0]); t1[j + 1] = f2bf(v[1]);
                t1[j + 2] = f2bf(v[2]); t1[j + 3] = f2bf(v[3]);
            }
            *(ushort8v*)&a_lds[row * 40 + koff] = t0;
            *(ushort8v*)&a_lds[row * 40 + koff + 8] = t1;
        }
        if (tid < 128) {
            int row = tid >> 1, koff = (tid & 1) * 16;
            ushort8v v0 = *(const ushort8v*)(wqk + (size_t)row * DIM + k0 + koff);
            ushort8v v1 = *(const ushort8v*)(wqk + (size_t)row * DIM + k0 + koff + 8);
            *(ushort8v*)&w_lds[row * 40 + koff] = v0;
            *(ushort8v*)&w_lds[row * 40 + koff + 8] = v1;
        }
        __syncthreads();
        bf16x8 a0 = *(const bf16x8*)&a_lds[(wave * 32 + l15) * 40 + quad * 8];
        bf16x8 a1 = *(const bf16x8*)&a_lds[(wave * 32 + 16 + l15) * 40 + quad * 8];
#pragma unroll
        for (int ni = 0; ni < 4; ++ni) {
            bf16x8 w = *(const bf16x8*)&w_lds[(ni * 16 + l15) * 40 + quad * 8];
            acc[0][ni] = __builtin_amdgcn_mfma_f32_16x16x32_bf16(a0, w, acc[0][ni], 0, 0, 0);
            acc[1][ni] = __builtin_amdgcn_mfma_f32_16x16x32_bf16(a1, w, acc[1][ni], 0, 0, 0);
        }
        __syncthreads();
    }
#pragma unroll
    for (int qi = 0; qi < 2; ++qi)
#pragma unroll
        for (int ni = 0; ni < 4; ++ni)
#pragma unroll
            for (int r = 0; r < 4; ++r) {
                int grow = rowbase + wave * 32 + qi * 16 + quad * 4 + r;
                xqk[(size_t)grow * 64 + ni * 16 + l15] = f2bf(acc[qi][ni][r]);
            }
}

// ---------------- K3 v2: attention. 512 thr, block = 128 q x 128 d; 64-key blocks ------
// Scores computed operand-swapped (A=xk, B=xq) with 32x32x16 so each lane holds
// consecutive keys for one query -> packed b64 P writes in PV A-layout. No max
// subtraction needed (|score/32| <= ~2.5 by Cauchy-Schwarz, rank 32).
__global__ __launch_bounds__(512, 4) void k_attn(const unsigned short* __restrict__ xqk,
                                                 const unsigned short* __restrict__ xt,
                                                 unsigned short* __restrict__ ctx) {
    __shared__ unsigned short xk_lds[2][64 * 40];    // 64 keys x 32 rank, dbuf
    __shared__ unsigned short xt_lds[2][128 * 72];   // 128 d x 64 keys, dbuf
    __shared__ unsigned short p_lds[128 * 72];       // P: 128 q x 64 keys
    __shared__ float den_lds[8 * 32];
    __shared__ float den_f[128];

    const int tid = threadIdx.x;
    const int wave = tid >> 6, lane = tid & 63, l31 = lane & 31, half = lane >> 5;
    const int qt = wave >> 1, kt = wave & 1;   // kt = score key-tile AND PV d-half
    const int dbase = blockIdx.x * 128;
    const int qbase = blockIdx.y * 128;
    const int b = blockIdx.z;

    // xq B-fragments (2 rank halves), loaded once from global (cols [0,32) of xqk)
    bf16x8 bq0, bq1;
    {
        const unsigned short* base = xqk + (size_t)(b * SEQ + qbase + qt * 32 + l31) * 64 + half * 8;
        bq0 = *(const bf16x8*)(base);
        bq1 = *(const bf16x8*)(base + 16);
    }

    f32x16 acc0, acc1;
#pragma unroll
    for (int i = 0; i < 16; ++i) { acc0[i] = 0.f; acc1[i] = 0.f; }
    float den = 0.f;
    const float SC = 0.045084220027779984f;   // 1/(32*ln2)

    auto stage = [&](int bb, int kkey) {
        {   // xk: 64 keys x 32 rank (cols [32,64) of xqk)
            int row = tid >> 3, koff = (tid & 7) * 4;
            ushort4v v = *(const ushort4v*)(xqk + (size_t)(b * SEQ + kkey + row) * 64 + 32 + koff);
            *(ushort4v*)&xk_lds[bb][row * 40 + koff] = v;
        }
#pragma unroll
        for (int i = 0; i < 2; ++i) {   // xt: 128 d x 64 keys
            int idx = i * 512 + tid;
            int drow = idx >> 3, kcol = (idx & 7) * 8;
            ushort8v v = *(const ushort8v*)(xt + (size_t)(b * DIM + dbase + drow) * SEQ + kkey + kcol);
            *(ushort8v*)&xt_lds[bb][drow * 72 + kcol] = v;
        }
    };

    stage(0, 0);
    __syncthreads();

    for (int kb = 0; kb < SEQ / 64; ++kb) {
        const int bb = kb & 1;
        if (kb + 1 < SEQ / 64) stage(bb ^ 1, (kb + 1) * 64);

        // scores: this wave's 32 q x 32 keys (tile kt), K=rank accumulated over 2 MFMAs
        f32x16 sc;
        {
            const int krow = (kt * 32 + l31) * 40 + half * 8;
            bf16x8 ak0 = *(const bf16x8*)&xk_lds[bb][krow];
            bf16x8 ak1 = *(const bf16x8*)&xk_lds[bb][krow + 16];
            f32x16 z;
#pragma unroll
            for (int i = 0; i < 16; ++i) z[i] = 0.f;
            sc = __builtin_amdgcn_mfma_f32_32x32x16_bf16(ak0, bq0, z, 0, 0, 0);
            sc = __builtin_amdgcn_mfma_f32_32x32x16_bf16(ak1, bq1, sc, 0, 0, 0);
        }

        // exp + denominator partial + packed P write (b64, PV A-layout)
#pragma unroll
        for (int g = 0; g < 4; ++g) {
            float e0 = exp2f(sc[4 * g + 0] * SC), e1 = exp2f(sc[4 * g + 1] * SC);
            float e2 = exp2f(sc[4 * g + 2] * SC), e3 = exp2f(sc[4 * g + 3] * SC);
            den += (e0 + e1) + (e2 + e3);
            uint2v dw; dw[0] = pk_bf16(e0, e1); dw[1] = pk_bf16(e2, e3);
            *(uint2v*)&p_lds[(qt * 32 + l31) * 72 + kt * 32 + g * 8 + half * 4] = dw;
        }
        __syncthreads();   // P visible; xt[bb] safe to read

        // PV: 4 key-subtiles x 2 d-tiles of 32
#pragma unroll
        for (int ks = 0; ks < 4; ++ks) {
            bf16x8 ap = *(const bf16x8*)&p_lds[(qt * 32 + l31) * 72 + ks * 16 + half * 8];
            bf16x8 bx0 = *(const bf16x8*)&xt_lds[bb][((kt * 2 + 0) * 32 + l31) * 72 + ks * 16 + half * 8];
            bf16x8 bx1 = *(const bf16x8*)&xt_lds[bb][((kt * 2 + 1) * 32 + l31) * 72 + ks * 16 + half * 8];
            acc0 = __builtin_amdgcn_mfma_f32_32x32x16_bf16(ap, bx0, acc0, 0, 0, 0);
            acc1 = __builtin_amdgcn_mfma_f32_32x32x16_bf16(ap, bx1, acc1, 0, 0, 0);
        }
        __syncthreads();   // PV done before next P write / buffer reuse
    }

    // denominator: combine halves (xor 32), then partner wave (other key tile)
    den += __shfl_xor(den, 32);
    if (half == 0) den_lds[wave * 32 + l31] = den;
    __syncthreads();
    float dtot = den + den_lds[(wave ^ 1) * 32 + l31];
    if (kt == 0 && half == 0) den_f[qt * 32 + l31] = 1.0f / dtot;
    __syncthreads();

    // epilogue: scale by 1/den and store ctx (bf16)
#pragma unroll
    for (int g = 0; g < 4; ++g) {
        f32x4 rd = *(const f32x4*)&den_f[qt * 32 + g * 8 + half * 4];
#pragma unroll
        for (int rr = 0; rr < 4; ++rr) {
            int qrow = qbase + qt * 32 + g * 8 + half * 4 + rr;
            float rs = rd[rr];
            size_t base = (size_t)(b * SEQ + qrow) * DIM + dbase;
            ctx[base + (kt * 2 + 0) * 32 + l31] = f2bf(acc0[4 * g + rr] * rs);
            ctx[base + (kt * 2 + 1) * 32 + l31] = f2bf(acc1[4 * g + rr] * rs);
        }
    }
}

// ---------------- K4: out = ctx @ VO  (via VO_t rows). M=16384,N=1024,K=1024 ----------
__global__ __launch_bounds__(256) void k_out(const unsigned short* __restrict__ ctx,
                                             const unsigned short* __restrict__ vot,
                                             float* __restrict__ out) {
    __shared__ unsigned short a_lds[128 * 40];
    __shared__ unsigned short b_lds[128 * 40];
    const int tid = threadIdx.x;
    const int wave = tid >> 6, lane = tid & 63, l15 = lane & 15, quad = lane >> 4;
    const int nbase = blockIdx.x * 128;
    const int rowbase = blockIdx.y * 128;

    f32x4 acc[2][8];
#pragma unroll
    for (int qi = 0; qi < 2; ++qi)
#pragma unroll
        for (int nt = 0; nt < 8; ++nt) acc[qi][nt] = (f32x4){0.f, 0.f, 0.f, 0.f};

    for (int k0 = 0; k0 < DIM; k0 += 32) {
        int row = tid >> 1, koff = (tid & 1) * 16;
        {
            ushort8v v0 = *(const ushort8v*)(ctx + (size_t)(rowbase + row) * DIM + k0 + koff);
            ushort8v v1 = *(const ushort8v*)(ctx + (size_t)(rowbase + row) * DIM + k0 + koff + 8);
            *(ushort8v*)&a_lds[row * 40 + koff] = v0;
            *(ushort8v*)&a_lds[row * 40 + koff + 8] = v1;
        }
        {
            ushort8v v0 = *(const ushort8v*)(vot + (size_t)(nbase + row) * DIM + k0 + koff);
            ushort8v v1 = *(const ushort8v*)(vot + (size_t)(nbase + row) * DIM + k0 + koff + 8);
            *(ushort8v*)&b_lds[row * 40 + koff] = v0;
            *(ushort8v*)&b_lds[row * 40 + koff + 8] = v1;
        }
        __syncthreads();
        bf16x8 a0 = *(const bf16x8*)&a_lds[(wave * 32 + l15) * 40 + quad * 8];
        bf16x8 a1 = *(const bf16x8*)&a_lds[(wave * 32 + 16 + l15) * 40 + quad * 8];
#pragma unroll
        for (int nt = 0; nt < 8; ++nt) {
            bf16x8 bn = *(const bf16x8*)&b_lds[(nt * 16 + l15) * 40 + quad * 8];
            acc[0][nt] = __builtin_amdgcn_mfma_f32_16x16x32_bf16(a0, bn, acc[0][nt], 0, 0, 0);
            acc[1][nt] = __builtin_amdgcn_mfma_f32_16x16x32_bf16(a1, bn, acc[1][nt], 0, 0, 0);
        }
        __syncthreads();
    }
#pragma unroll
    for (int qi = 0; qi < 2; ++qi)
#pragma unroll
        for (int nt = 0; nt < 8; ++nt)
#pragma unroll
            for (int r = 0; r < 4; ++r) {
                int grow = rowbase + wave * 32 + qi * 16 + quad * 4 + r;
                out[(size_t)grow * DIM + nbase + nt * 16 + l15] = acc[qi][nt][r];
            }
}

extern "C" void kernel_launch(void* const* d_in, const int* in_sizes, int n_in,
                              void* d_out, int out_size, void* d_ws, size_t ws_size,
                              hipStream_t stream) {
    const float* x  = (const float*)d_in[0];
    const float* Q  = (const float*)d_in[1];
    const float* K  = (const float*)d_in[2];
    const float* VO = (const float*)d_in[3];
    float* out = (float*)d_out;

    char* ws = (char*)d_ws;
    unsigned short* wqk = (unsigned short*)(ws + 0);          // 64x1024 bf16      = 128 KB
    unsigned short* vot = (unsigned short*)(ws + 131072);     // 1024x1024 bf16    = 2 MB
    unsigned short* xqk = (unsigned short*)(ws + 2228224);    // 16384x64 bf16     = 2 MB
    unsigned short* xt  = (unsigned short*)(ws + 4325376);    // 4x1024x4096 bf16  = 32 MB
    unsigned short* ctx = (unsigned short*)(ws + 37879808);   // 16384x1024 bf16   = 32 MB

    k_cvt_qk<<<256, 256, 0, stream>>>(Q, K, wqk);
    k_transpose_cvt<<<dim3(16, 16, 1), 256, 0, stream>>>(VO, vot, 1024, 1024, 0, 0);
    k_transpose_cvt<<<dim3(16, 64, BATCH), 256, 0, stream>>>(x, xt, SEQ, DIM, SEQ * DIM, DIM * SEQ);
    k_proj<<<128, 256, 0, stream>>>(x, wqk, xqk);
    k_attn<<<dim3(DIM / 128, SEQ / 128, BATCH), 512, 0, stream>>>(xqk, xt, ctx);
    k_out<<<dim3(DIM / 128, 16384 / 128, 1), 256, 0, stream>>>(ctx, vot, out);
}

// Round 3
// 434.687 us; speedup vs baseline: 1.3388x; 1.0805x over previous
//
#include <hip/hip_runtime.h>
#include <hip/hip_bf16.h>

#define DIM  1024
#define RANK 32
#define BATCH 4
#define SEQ  4096
#define MTOT (BATCH * SEQ)   // 16384

typedef short bf16x8 __attribute__((ext_vector_type(8)));          // MFMA A/B frag (8 bf16)
typedef float f32x4 __attribute__((ext_vector_type(4)));           // 16x16 MFMA C/D frag
typedef float f32x16 __attribute__((ext_vector_type(16)));         // 32x32 MFMA C/D frag
typedef unsigned short ushort8v __attribute__((ext_vector_type(8)));
typedef unsigned int uint2v __attribute__((ext_vector_type(2)));

__device__ inline unsigned short f2bf(float f) {
    union { float f; unsigned int u; } v; v.f = f;
    return (unsigned short)((v.u + 0x7FFFu + ((v.u >> 16) & 1u)) >> 16);  // RNE
}

__device__ inline unsigned int pk_bf16(float a, float b) {
    __hip_bfloat162 h = __float22bfloat162_rn(make_float2(a, b));
    unsigned int u; __builtin_memcpy(&u, &h, 4);
    return u;
}

// async global->LDS, 16B per lane; data lands at lds_base + lane*16 (wave-uniform base)
__device__ inline void gl_lds16(const unsigned short* g, unsigned short* l) {
    __builtin_amdgcn_global_load_lds(
        (const __attribute__((address_space(1))) unsigned int*)g,
        (__attribute__((address_space(3))) unsigned int*)l, 16, 0, 0);
}

// ---------------- K0: pack Q*SC, K (fp32 32x1024 each) -> wqk bf16 (64x1024) -----------
// SC = 1/(32*ln2) folded into Q so scores come out as exp2 arguments directly.
__global__ __launch_bounds__(256) void k_cvt_qk(const float* __restrict__ Q,
                                                const float* __restrict__ K,
                                                unsigned short* __restrict__ wqk) {
    int i = blockIdx.x * 256 + threadIdx.x;        // 65536 total
    int row = i >> 10, col = i & 1023;
    const float SC = 0.045084220027779984f;        // 1/(32*ln2)
    float v = (row < RANK) ? Q[row * DIM + col] * SC : K[(row - RANK) * DIM + col];
    wqk[i] = f2bf(v);
}

// ---------------- K1: tiled transpose + fp32->bf16 (VO -> vot[e][d]) -------------------
__global__ __launch_bounds__(256) void k_transpose_cvt(const float* __restrict__ in,
                                                       unsigned short* __restrict__ out,
                                                       int R, int C) {
    __shared__ float tile[64][65];
    const int tid = threadIdx.x;
    const int c0 = blockIdx.x * 64, r0 = blockIdx.y * 64;
    {
        int c = (tid & 15) * 4;
#pragma unroll
        for (int i = 0; i < 4; ++i) {
            int r = (tid >> 4) + i * 16;
            f32x4 v = *(const f32x4*)(in + (size_t)(r0 + r) * C + c0 + c);
            tile[r][c + 0] = v[0]; tile[r][c + 1] = v[1];
            tile[r][c + 2] = v[2]; tile[r][c + 3] = v[3];
        }
    }
    __syncthreads();
    {
        int r = (tid & 15) * 4;
#pragma unroll
        for (int i = 0; i < 4; ++i) {
            int c = (tid >> 4) + i * 16;
            unsigned short o0 = f2bf(tile[r + 0][c]), o1 = f2bf(tile[r + 1][c]);
            unsigned short o2 = f2bf(tile[r + 2][c]), o3 = f2bf(tile[r + 3][c]);
            unsigned short* p = out + (size_t)(c0 + c) * R + r0 + r;
            p[0] = o0; p[1] = o1; p[2] = o2; p[3] = o3;
        }
    }
}

// ---------------- K2: x fp32 -> xbf bf16, row-major passthrough ------------------------
__global__ __launch_bounds__(256) void k_xbf(const float* __restrict__ x,
                                             unsigned short* __restrict__ xbf) {
    size_t i = ((size_t)blockIdx.x * 256 + threadIdx.x) * 8;
    f32x4 v0 = *(const f32x4*)(x + i);
    f32x4 v1 = *(const f32x4*)(x + i + 4);
    ushort8v o;
    o[0] = f2bf(v0[0]); o[1] = f2bf(v0[1]); o[2] = f2bf(v0[2]); o[3] = f2bf(v0[3]);
    o[4] = f2bf(v1[0]); o[5] = f2bf(v1[1]); o[6] = f2bf(v1[2]); o[7] = f2bf(v1[3]);
    *(ushort8v*)(xbf + i) = o;
}

// ---------------- K3: xqk = xbf @ wqk^T  (M=16384, N=64, K=1024), bf16 out -------------
__global__ __launch_bounds__(256) void k_proj(const unsigned short* __restrict__ xbf,
                                              const unsigned short* __restrict__ wqk,
                                              unsigned short* __restrict__ xqk) {
    __shared__ __align__(16) unsigned short a_lds[128 * 32];
    __shared__ __align__(16) unsigned short w_lds[64 * 32];
    const int tid = threadIdx.x;
    const int w = tid >> 6, lane = tid & 63, l15 = lane & 15, quad = lane >> 4;
    const int wm = w & 1, wn = w >> 1;
    const int rowbase = blockIdx.x * 128;

    f32x4 acc[4][2];
#pragma unroll
    for (int mt = 0; mt < 4; ++mt)
#pragma unroll
        for (int nt = 0; nt < 2; ++nt) acc[mt][nt] = (f32x4){0.f, 0.f, 0.f, 0.f};

    const unsigned short* Ab = xbf + (size_t)(rowbase + w * 32 + (lane >> 2)) * DIM + (lane & 3) * 8;
    const unsigned short* Wb = wqk + (size_t)(w * 16 + (lane >> 2)) * DIM + (lane & 3) * 8;

    for (int k0 = 0; k0 < DIM; k0 += 32) {
        gl_lds16(Ab + k0, &a_lds[(w * 32) * 32]);
        gl_lds16(Ab + (size_t)16 * DIM + k0, &a_lds[(w * 32 + 16) * 32]);
        gl_lds16(Wb + k0, &w_lds[(w * 16) * 32]);
        __syncthreads();
        bf16x8 am[4], bn[2];
#pragma unroll
        for (int mt = 0; mt < 4; ++mt)
            am[mt] = *(const bf16x8*)&a_lds[(wm * 64 + mt * 16 + l15) * 32 + quad * 8];
#pragma unroll
        for (int nt = 0; nt < 2; ++nt)
            bn[nt] = *(const bf16x8*)&w_lds[(wn * 32 + nt * 16 + l15) * 32 + quad * 8];
#pragma unroll
        for (int mt = 0; mt < 4; ++mt)
#pragma unroll
            for (int nt = 0; nt < 2; ++nt)
                acc[mt][nt] = __builtin_amdgcn_mfma_f32_16x16x32_bf16(am[mt], bn[nt], acc[mt][nt], 0, 0, 0);
        __syncthreads();
    }
#pragma unroll
    for (int mt = 0; mt < 4; ++mt)
#pragma unroll
        for (int nt = 0; nt < 2; ++nt)
#pragma unroll
            for (int r = 0; r < 4; ++r) {
                int grow = rowbase + wm * 64 + mt * 16 + quad * 4 + r;
                xqk[(size_t)grow * 64 + wn * 32 + nt * 16 + l15] = f2bf(acc[mt][nt][r]);
            }
}

// ---------------- K4: P = exp2(xq . xk) bf16 (materialized), den partials --------------
// grid (SEQ/64 q-tiles, 8 key-chunks of 512, B). No max-subtraction needed
// (|exp2 arg| <= ~3.6: rank-32 Cauchy-Schwarz bound; validated rounds 1-2).
__global__ __launch_bounds__(256) void k_score(const unsigned short* __restrict__ xqk,
                                               unsigned short* __restrict__ P,
                                               float* __restrict__ den_part) {
    __shared__ __align__(16) unsigned short xk_lds[128 * 32];
    __shared__ __align__(16) unsigned short p_lds[64 * 136];   // stride 136 shorts = 272B (16B-aligned)
    __shared__ float denp[4][64];
    const int tid = threadIdx.x;
    const int w = tid >> 6, lane = tid & 63, l31 = lane & 31, half = lane >> 5;
    const int qbase = blockIdx.x * 64;
    const int kc = blockIdx.y;
    const int b = blockIdx.z;

    bf16x8 bq[2][2];
#pragma unroll
    for (int qt = 0; qt < 2; ++qt) {
        const unsigned short* base = xqk + (size_t)(b * SEQ + qbase + qt * 32 + l31) * 64 + half * 8;
        bq[qt][0] = *(const bf16x8*)(base);
        bq[qt][1] = *(const bf16x8*)(base + 16);
    }
    float dacc[2] = {0.f, 0.f};

    const unsigned short* XKb = xqk + (size_t)(b * SEQ + kc * 512 + w * 32 + (lane >> 2)) * 64 + 32 + (lane & 3) * 8;

    for (int it = 0; it < 4; ++it) {
        const int kkey = kc * 512 + it * 128;
        gl_lds16(XKb + (size_t)(it * 128) * 64, &xk_lds[(w * 32) * 32]);
        gl_lds16(XKb + (size_t)(it * 128 + 16) * 64, &xk_lds[(w * 32 + 16) * 32]);
        __syncthreads();

        bf16x8 ak0 = *(const bf16x8*)&xk_lds[(w * 32 + l31) * 32 + half * 8];
        bf16x8 ak1 = *(const bf16x8*)&xk_lds[(w * 32 + l31) * 32 + 16 + half * 8];
        f32x16 z;
#pragma unroll
        for (int i = 0; i < 16; ++i) z[i] = 0.f;
#pragma unroll
        for (int qt = 0; qt < 2; ++qt) {
            f32x16 sc = __builtin_amdgcn_mfma_f32_32x32x16_bf16(ak0, bq[qt][0], z, 0, 0, 0);
            sc = __builtin_amdgcn_mfma_f32_32x32x16_bf16(ak1, bq[qt][1], sc, 0, 0, 0);
#pragma unroll
            for (int g = 0; g < 4; ++g) {
                float e0 = exp2f(sc[4 * g + 0]), e1 = exp2f(sc[4 * g + 1]);
                float e2 = exp2f(sc[4 * g + 2]), e3 = exp2f(sc[4 * g + 3]);
                dacc[qt] += (e0 + e1) + (e2 + e3);
                uint2v dw; dw[0] = pk_bf16(e0, e1); dw[1] = pk_bf16(e2, e3);
                *(uint2v*)&p_lds[(qt * 32 + l31) * 136 + w * 32 + g * 8 + half * 4] = dw;
            }
        }
        __syncthreads();
        // coalesced P store: 64 q x 128 keys
#pragma unroll
        for (int i = 0; i < 4; ++i) {
            int row = i * 16 + (tid >> 4);
            int col = (tid & 15) * 8;
            ushort8v v = *(const ushort8v*)&p_lds[row * 136 + col];
            *(ushort8v*)(P + (size_t)(b * SEQ + qbase + row) * SEQ + kkey + col) = v;
        }
    }
#pragma unroll
    for (int qt = 0; qt < 2; ++qt) {
        float d = dacc[qt];
        d += __shfl_xor(d, 32);
        if (half == 0) denp[w][qt * 32 + l31] = d;
    }
    __syncthreads();
    if (tid < 64) {
        float s = denp[0][tid] + denp[1][tid] + denp[2][tid] + denp[3][tid];
        den_part[(size_t)kc * MTOT + b * SEQ + qbase + tid] = s;
    }
}

// ---------------- K5: xvoT[b][e][u] = (x @ VO)^T  (M=e 1024, N=u 4096, K=d 1024) -------
__global__ __launch_bounds__(256) void k_xvo(const unsigned short* __restrict__ vot,
                                             const unsigned short* __restrict__ xbf,
                                             unsigned short* __restrict__ xvoT) {
    __shared__ __align__(16) unsigned short a_lds[128 * 32];
    __shared__ __align__(16) unsigned short b_lds[128 * 32];
    const int tid = threadIdx.x;
    const int w = tid >> 6, lane = tid & 63, l15 = lane & 15, quad = lane >> 4;
    const int wm = w & 1, wn = w >> 1;
    const int ubase = blockIdx.x * 128;
    const int ebase = blockIdx.y * 128;
    const int b = blockIdx.z;

    f32x4 acc[4][4];
#pragma unroll
    for (int mt = 0; mt < 4; ++mt)
#pragma unroll
        for (int nt = 0; nt < 4; ++nt) acc[mt][nt] = (f32x4){0.f, 0.f, 0.f, 0.f};

    const unsigned short* Ab = vot + (size_t)(ebase + w * 32 + (lane >> 2)) * DIM + (lane & 3) * 8;
    const unsigned short* Bb = xbf + (size_t)(b * SEQ + ubase + w * 32 + (lane >> 2)) * DIM + (lane & 3) * 8;

    for (int k0 = 0; k0 < DIM; k0 += 32) {
        gl_lds16(Ab + k0, &a_lds[(w * 32) * 32]);
        gl_lds16(Ab + (size_t)16 * DIM + k0, &a_lds[(w * 32 + 16) * 32]);
        gl_lds16(Bb + k0, &b_lds[(w * 32) * 32]);
        gl_lds16(Bb + (size_t)16 * DIM + k0, &b_lds[(w * 32 + 16) * 32]);
        __syncthreads();
        bf16x8 am[4], bn[4];
#pragma unroll
        for (int mt = 0; mt < 4; ++mt)
            am[mt] = *(const bf16x8*)&a_lds[(wm * 64 + mt * 16 + l15) * 32 + quad * 8];
#pragma unroll
        for (int nt = 0; nt < 4; ++nt)
            bn[nt] = *(const bf16x8*)&b_lds[(wn * 64 + nt * 16 + l15) * 32 + quad * 8];
#pragma unroll
        for (int mt = 0; mt < 4; ++mt)
#pragma unroll
            for (int nt = 0; nt < 4; ++nt)
                acc[mt][nt] = __builtin_amdgcn_mfma_f32_16x16x32_bf16(am[mt], bn[nt], acc[mt][nt], 0, 0, 0);
        __syncthreads();
    }
#pragma unroll
    for (int mt = 0; mt < 4; ++mt)
#pragma unroll
        for (int nt = 0; nt < 4; ++nt)
#pragma unroll
            for (int r = 0; r < 4; ++r) {
                int e = ebase + wm * 64 + mt * 16 + quad * 4 + r;
                int u = ubase + wn * 64 + nt * 16 + l15;
                xvoT[(size_t)(b * DIM + e) * SEQ + u] = f2bf(acc[mt][nt][r]);
            }
}

// ---------------- K6: out = (P @ xvoT^T) * (1/den)  (M=16384, N=1024, K=4096) ----------
__global__ __launch_bounds__(256) void k_pv(const unsigned short* __restrict__ P,
                                            const unsigned short* __restrict__ xvoT,
                                            const float* __restrict__ den_part,
                                            float* __restrict__ out) {
    __shared__ __align__(16) unsigned short a_lds[128 * 32];
    __shared__ __align__(16) unsigned short b_lds[128 * 32];
    __shared__ float rden[128];
    const int tid = threadIdx.x;
    const int w = tid >> 6, lane = tid & 63, l15 = lane & 15, quad = lane >> 4;
    const int wm = w & 1, wn = w >> 1;
    const int rowbase = blockIdx.y * 128;     // global q row in [0,16384)
    const int ebase = blockIdx.x * 128;
    const int b = rowbase >> 12;

    if (tid < 128) {
        float s = 0.f;
#pragma unroll
        for (int i = 0; i < 8; ++i) s += den_part[(size_t)i * MTOT + rowbase + tid];
        rden[tid] = 1.0f / s;
    }

    f32x4 acc[4][4];
#pragma unroll
    for (int mt = 0; mt < 4; ++mt)
#pragma unroll
        for (int nt = 0; nt < 4; ++nt) acc[mt][nt] = (f32x4){0.f, 0.f, 0.f, 0.f};

    const unsigned short* Ab = P + (size_t)(rowbase + w * 32 + (lane >> 2)) * SEQ + (lane & 3) * 8;
    const unsigned short* Bb = xvoT + (size_t)(b * DIM + ebase + w * 32 + (lane >> 2)) * SEQ + (lane & 3) * 8;

    for (int k0 = 0; k0 < SEQ; k0 += 32) {
        gl_lds16(Ab + k0, &a_lds[(w * 32) * 32]);
        gl_lds16(Ab + (size_t)16 * SEQ + k0, &a_lds[(w * 32 + 16) * 32]);
        gl_lds16(Bb + k0, &b_lds[(w * 32) * 32]);
        gl_lds16(Bb + (size_t)16 * SEQ + k0, &b_lds[(w * 32 + 16) * 32]);
        __syncthreads();
        bf16x8 am[4], bn[4];
#pragma unroll
        for (int mt = 0; mt < 4; ++mt)
            am[mt] = *(const bf16x8*)&a_lds[(wm * 64 + mt * 16 + l15) * 32 + quad * 8];
#pragma unroll
        for (int nt = 0; nt < 4; ++nt)
            bn[nt] = *(const bf16x8*)&b_lds[(wn * 64 + nt * 16 + l15) * 32 + quad * 8];
#pragma unroll
        for (int mt = 0; mt < 4; ++mt)
#pragma unroll
            for (int nt = 0; nt < 4; ++nt)
                acc[mt][nt] = __builtin_amdgcn_mfma_f32_16x16x32_bf16(am[mt], bn[nt], acc[mt][nt], 0, 0, 0);
        __syncthreads();
    }
#pragma unroll
    for (int mt = 0; mt < 4; ++mt)
#pragma unroll
        for (int nt = 0; nt < 4; ++nt)
#pragma unroll
            for (int r = 0; r < 4; ++r) {
                int lr = wm * 64 + mt * 16 + quad * 4 + r;
                int e = ebase + wn * 64 + nt * 16 + l15;
                out[(size_t)(rowbase + lr) * DIM + e] = acc[mt][nt][r] * rden[lr];
            }
}

extern "C" void kernel_launch(void* const* d_in, const int* in_sizes, int n_in,
                              void* d_out, int out_size, void* d_ws, size_t ws_size,
                              hipStream_t stream) {
    const float* x  = (const float*)d_in[0];
    const float* Q  = (const float*)d_in[1];
    const float* K  = (const float*)d_in[2];
    const float* VO = (const float*)d_in[3];
    float* out = (float*)d_out;

    char* ws = (char*)d_ws;
    unsigned short* wqk  = (unsigned short*)(ws + 0);           // 64x1024 bf16        128 KB
    unsigned short* vot  = (unsigned short*)(ws + 131072);      // 1024x1024 bf16        2 MB
    unsigned short* xqk  = (unsigned short*)(ws + 2228224);     // 16384x64 bf16         2 MB
    unsigned short* xbf  = (unsigned short*)(ws + 4325376);     // 16384x1024 bf16      32 MB
    unsigned short* xvoT = (unsigned short*)(ws + 37879808);    // 4x1024x4096 bf16     32 MB
    float*          denp = (float*)(ws + 71434240);             // 8x16384 fp32        512 KB
    unsigned short* P    = (unsigned short*)(ws + 71958528);    // 4x4096x4096 bf16    128 MB
    // total ~197 MB

    k_cvt_qk<<<256, 256, 0, stream>>>(Q, K, wqk);
    k_transpose_cvt<<<dim3(16, 16, 1), 256, 0, stream>>>(VO, vot, 1024, 1024);
    k_xbf<<<8192, 256, 0, stream>>>(x, xbf);
    k_proj<<<128, 256, 0, stream>>>(xbf, wqk, xqk);
    k_score<<<dim3(SEQ / 64, 8, BATCH), 256, 0, stream>>>(xqk, P, denp);
    k_xvo<<<dim3(32, 8, BATCH), 256, 0, stream>>>(vot, xbf, xvoT);
    k_pv<<<dim3(8, 128, 1), 256, 0, stream>>>(P, xvoT, denp, out);
}

// Round 4
// 337.275 us; speedup vs baseline: 1.7255x; 1.2888x over previous
//
#include <hip/hip_runtime.h>
#include <hip/hip_bf16.h>

#define DIM  1024
#define RANK 32
#define BATCH 4
#define SEQ  4096
#define MTOT (BATCH * SEQ)   // 16384

typedef short bf16x8 __attribute__((ext_vector_type(8)));          // MFMA A/B frag (8 bf16)
typedef float f32x4 __attribute__((ext_vector_type(4)));           // 16x16 MFMA C/D frag
typedef float f32x16 __attribute__((ext_vector_type(16)));         // 32x32 MFMA C/D frag
typedef unsigned short ushort8v __attribute__((ext_vector_type(8)));
typedef unsigned int uint2v __attribute__((ext_vector_type(2)));

__device__ inline unsigned short f2bf(float f) {
    union { float f; unsigned int u; } v; v.f = f;
    return (unsigned short)((v.u + 0x7FFFu + ((v.u >> 16) & 1u)) >> 16);  // RNE
}

__device__ inline unsigned int pk_bf16(float a, float b) {
    __hip_bfloat162 h = __float22bfloat162_rn(make_float2(a, b));
    unsigned int u; __builtin_memcpy(&u, &h, 4);
    return u;
}

// async global->LDS, 16B per lane; data lands at lds_base + lane*16 (wave-uniform base)
__device__ inline void gl_lds16(const unsigned short* g, unsigned short* l) {
    __builtin_amdgcn_global_load_lds(
        (const __attribute__((address_space(1))) unsigned int*)g,
        (__attribute__((address_space(3))) unsigned int*)l, 16, 0, 0);
}

// ---------------- K0: pack Q*SC, K (fp32 32x1024 each) -> wqk bf16 (64x1024) -----------
__global__ __launch_bounds__(256) void k_cvt_qk(const float* __restrict__ Q,
                                                const float* __restrict__ K,
                                                unsigned short* __restrict__ wqk) {
    int i = blockIdx.x * 256 + threadIdx.x;        // 65536 total
    int row = i >> 10, col = i & 1023;
    const float SC = 0.045084220027779984f;        // 1/(32*ln2)
    float v = (row < RANK) ? Q[row * DIM + col] * SC : K[(row - RANK) * DIM + col];
    wqk[i] = f2bf(v);
}

// ---------------- K1: tiled transpose + fp32->bf16 (VO -> vot[e][d]) -------------------
__global__ __launch_bounds__(256) void k_transpose_cvt(const float* __restrict__ in,
                                                       unsigned short* __restrict__ out,
                                                       int R, int C) {
    __shared__ float tile[64][65];
    const int tid = threadIdx.x;
    const int c0 = blockIdx.x * 64, r0 = blockIdx.y * 64;
    {
        int c = (tid & 15) * 4;
#pragma unroll
        for (int i = 0; i < 4; ++i) {
            int r = (tid >> 4) + i * 16;
            f32x4 v = *(const f32x4*)(in + (size_t)(r0 + r) * C + c0 + c);
            tile[r][c + 0] = v[0]; tile[r][c + 1] = v[1];
            tile[r][c + 2] = v[2]; tile[r][c + 3] = v[3];
        }
    }
    __syncthreads();
    {
        int r = (tid & 15) * 4;
#pragma unroll
        for (int i = 0; i < 4; ++i) {
            int c = (tid >> 4) + i * 16;
            unsigned short o0 = f2bf(tile[r + 0][c]), o1 = f2bf(tile[r + 1][c]);
            unsigned short o2 = f2bf(tile[r + 2][c]), o3 = f2bf(tile[r + 3][c]);
            unsigned short* p = out + (size_t)(c0 + c) * R + r0 + r;
            p[0] = o0; p[1] = o1; p[2] = o2; p[3] = o3;
        }
    }
}

// ---------------- K2: x fp32 -> xbf bf16, row-major passthrough ------------------------
__global__ __launch_bounds__(256) void k_xbf(const float* __restrict__ x,
                                             unsigned short* __restrict__ xbf) {
    size_t i = ((size_t)blockIdx.x * 256 + threadIdx.x) * 8;
    f32x4 v0 = *(const f32x4*)(x + i);
    f32x4 v1 = *(const f32x4*)(x + i + 4);
    ushort8v o;
    o[0] = f2bf(v0[0]); o[1] = f2bf(v0[1]); o[2] = f2bf(v0[2]); o[3] = f2bf(v0[3]);
    o[4] = f2bf(v1[0]); o[5] = f2bf(v1[1]); o[6] = f2bf(v1[2]); o[7] = f2bf(v1[3]);
    *(ushort8v*)(xbf + i) = o;
}

// ---------------- K3: xqk = xbf @ wqk^T  (M=16384, N=64, K=1024), bf16 out -------------
__global__ __launch_bounds__(256) void k_proj(const unsigned short* __restrict__ xbf,
                                              const unsigned short* __restrict__ wqk,
                                              unsigned short* __restrict__ xqk) {
    __shared__ __align__(16) unsigned short a_lds[128 * 32];
    __shared__ __align__(16) unsigned short w_lds[64 * 32];
    const int tid = threadIdx.x;
    const int w = tid >> 6, lane = tid & 63, l15 = lane & 15, quad = lane >> 4;
    const int wm = w & 1, wn = w >> 1;
    const int rowbase = blockIdx.x * 128;

    f32x4 acc[4][2];
#pragma unroll
    for (int mt = 0; mt < 4; ++mt)
#pragma unroll
        for (int nt = 0; nt < 2; ++nt) acc[mt][nt] = (f32x4){0.f, 0.f, 0.f, 0.f};

    const unsigned short* Ab = xbf + (size_t)(rowbase + w * 32 + (lane >> 2)) * DIM + (lane & 3) * 8;
    const unsigned short* Wb = wqk + (size_t)(w * 16 + (lane >> 2)) * DIM + (lane & 3) * 8;

    for (int k0 = 0; k0 < DIM; k0 += 32) {
        gl_lds16(Ab + k0, &a_lds[(w * 32) * 32]);
        gl_lds16(Ab + (size_t)16 * DIM + k0, &a_lds[(w * 32 + 16) * 32]);
        gl_lds16(Wb + k0, &w_lds[(w * 16) * 32]);
        __syncthreads();
        bf16x8 am[4], bn[2];
#pragma unroll
        for (int mt = 0; mt < 4; ++mt)
            am[mt] = *(const bf16x8*)&a_lds[(wm * 64 + mt * 16 + l15) * 32 + quad * 8];
#pragma unroll
        for (int nt = 0; nt < 2; ++nt)
            bn[nt] = *(const bf16x8*)&w_lds[(wn * 32 + nt * 16 + l15) * 32 + quad * 8];
#pragma unroll
        for (int mt = 0; mt < 4; ++mt)
#pragma unroll
            for (int nt = 0; nt < 2; ++nt)
                acc[mt][nt] = __builtin_amdgcn_mfma_f32_16x16x32_bf16(am[mt], bn[nt], acc[mt][nt], 0, 0, 0);
        __syncthreads();
    }
#pragma unroll
    for (int mt = 0; mt < 4; ++mt)
#pragma unroll
        for (int nt = 0; nt < 2; ++nt)
#pragma unroll
            for (int r = 0; r < 4; ++r) {
                int grow = rowbase + wm * 64 + mt * 16 + quad * 4 + r;
                xqk[(size_t)grow * 64 + wn * 32 + nt * 16 + l15] = f2bf(acc[mt][nt][r]);
            }
}

// ---------------- K4: P = exp2(xq . xk) bf16 (materialized), den partials --------------
__global__ __launch_bounds__(256) void k_score(const unsigned short* __restrict__ xqk,
                                               unsigned short* __restrict__ P,
                                               float* __restrict__ den_part) {
    __shared__ __align__(16) unsigned short xk_lds[128 * 32];
    __shared__ __align__(16) unsigned short p_lds[64 * 136];
    __shared__ float denp[4][64];
    const int tid = threadIdx.x;
    const int w = tid >> 6, lane = tid & 63, l31 = lane & 31, half = lane >> 5;
    const int qbase = blockIdx.x * 64;
    const int kc = blockIdx.y;
    const int b = blockIdx.z;

    bf16x8 bq[2][2];
#pragma unroll
    for (int qt = 0; qt < 2; ++qt) {
        const unsigned short* base = xqk + (size_t)(b * SEQ + qbase + qt * 32 + l31) * 64 + half * 8;
        bq[qt][0] = *(const bf16x8*)(base);
        bq[qt][1] = *(const bf16x8*)(base + 16);
    }
    float dacc[2] = {0.f, 0.f};

    const unsigned short* XKb = xqk + (size_t)(b * SEQ + kc * 512 + w * 32 + (lane >> 2)) * 64 + 32 + (lane & 3) * 8;

    for (int it = 0; it < 4; ++it) {
        const int kkey = kc * 512 + it * 128;
        gl_lds16(XKb + (size_t)(it * 128) * 64, &xk_lds[(w * 32) * 32]);
        gl_lds16(XKb + (size_t)(it * 128 + 16) * 64, &xk_lds[(w * 32 + 16) * 32]);
        __syncthreads();

        bf16x8 ak0 = *(const bf16x8*)&xk_lds[(w * 32 + l31) * 32 + half * 8];
        bf16x8 ak1 = *(const bf16x8*)&xk_lds[(w * 32 + l31) * 32 + 16 + half * 8];
        f32x16 z;
#pragma unroll
        for (int i = 0; i < 16; ++i) z[i] = 0.f;
#pragma unroll
        for (int qt = 0; qt < 2; ++qt) {
            f32x16 sc = __builtin_amdgcn_mfma_f32_32x32x16_bf16(ak0, bq[qt][0], z, 0, 0, 0);
            sc = __builtin_amdgcn_mfma_f32_32x32x16_bf16(ak1, bq[qt][1], sc, 0, 0, 0);
#pragma unroll
            for (int g = 0; g < 4; ++g) {
                float e0 = exp2f(sc[4 * g + 0]), e1 = exp2f(sc[4 * g + 1]);
                float e2 = exp2f(sc[4 * g + 2]), e3 = exp2f(sc[4 * g + 3]);
                dacc[qt] += (e0 + e1) + (e2 + e3);
                uint2v dw; dw[0] = pk_bf16(e0, e1); dw[1] = pk_bf16(e2, e3);
                *(uint2v*)&p_lds[(qt * 32 + l31) * 136 + w * 32 + g * 8 + half * 4] = dw;
            }
        }
        __syncthreads();
#pragma unroll
        for (int i = 0; i < 4; ++i) {
            int row = i * 16 + (tid >> 4);
            int col = (tid & 15) * 8;
            ushort8v v = *(const ushort8v*)&p_lds[row * 136 + col];
            *(ushort8v*)(P + (size_t)(b * SEQ + qbase + row) * SEQ + kkey + col) = v;
        }
    }
#pragma unroll
    for (int qt = 0; qt < 2; ++qt) {
        float d = dacc[qt];
        d += __shfl_xor(d, 32);
        if (half == 0) denp[w][qt * 32 + l31] = d;
    }
    __syncthreads();
    if (tid < 64) {
        float s = denp[0][tid] + denp[1][tid] + denp[2][tid] + denp[3][tid];
        den_part[(size_t)kc * MTOT + b * SEQ + qbase + tid] = s;
    }
}

// ---------------- K5 v2: xvoT[b][e][u] = (x @ VO)^T. 128e x 256u tile, BK=64, 32x32 ----
// XOR chunk swizzle: staged slot s holds global chunk s^(row&7); frag read uses
// slot (ks*2+half)^(l31&7) -> conflict-free b128 (8 bank-cycles).
__global__ __launch_bounds__(512, 4) void k_xvo(const unsigned short* __restrict__ vot,
                                                const unsigned short* __restrict__ xbf,
                                                unsigned short* __restrict__ xvoT) {
    __shared__ __align__(16) unsigned short a_lds[128 * 64];   // 128 e-rows x 128B
    __shared__ __align__(16) unsigned short b_lds[256 * 64];   // 256 u-rows x 128B
    const int tid = threadIdx.x;
    const int w = tid >> 6, lane = tid & 63, l31 = lane & 31, half = lane >> 5;
    const int wm = w & 1, wn = w >> 1;
    const int ubase = blockIdx.x * 256;
    const int ebase = blockIdx.y * 128;
    const int b = blockIdx.z;

    f32x16 acc[2][2];
#pragma unroll
    for (int at = 0; at < 2; ++at)
#pragma unroll
        for (int bt = 0; bt < 2; ++bt)
#pragma unroll
            for (int i = 0; i < 16; ++i) acc[at][bt][i] = 0.f;

    const int sub = lane >> 3;                 // 0..7 rows within a stage call
    const int g = (lane & 7) ^ (sub & 7);      // swizzled global chunk for this lane
    const int Ra = w * 16 + sub;               // A rows (c adds 8; &7 invariant)
    const int Rb = w * 32 + sub;               // B rows (c adds 8)
    const unsigned short* Ap = vot + (size_t)(ebase + Ra) * DIM + g * 8;
    const unsigned short* Bp = xbf + (size_t)(b * SEQ + ubase + Rb) * DIM + g * 8;

    for (int k0 = 0; k0 < DIM; k0 += 64) {
#pragma unroll
        for (int c = 0; c < 2; ++c)
            gl_lds16(Ap + (size_t)(c * 8) * DIM + k0, &a_lds[(w * 16 + c * 8) * 64]);
#pragma unroll
        for (int c = 0; c < 4; ++c)
            gl_lds16(Bp + (size_t)(c * 8) * DIM + k0, &b_lds[(w * 32 + c * 8) * 64]);
        __syncthreads();

        const int abase = (wm * 64 + l31) * 64;
        const int bbase = (wn * 64 + l31) * 64;
#pragma unroll
        for (int ks = 0; ks < 4; ++ks) {
            const int soff = ((ks * 2 + half) ^ (l31 & 7)) * 8;
            bf16x8 a0 = *(const bf16x8*)&a_lds[abase + soff];
            bf16x8 a1 = *(const bf16x8*)&a_lds[abase + 2048 + soff];
            bf16x8 b0 = *(const bf16x8*)&b_lds[bbase + soff];
            bf16x8 b1 = *(const bf16x8*)&b_lds[bbase + 2048 + soff];
            acc[0][0] = __builtin_amdgcn_mfma_f32_32x32x16_bf16(a0, b0, acc[0][0], 0, 0, 0);
            acc[0][1] = __builtin_amdgcn_mfma_f32_32x32x16_bf16(a0, b1, acc[0][1], 0, 0, 0);
            acc[1][0] = __builtin_amdgcn_mfma_f32_32x32x16_bf16(a1, b0, acc[1][0], 0, 0, 0);
            acc[1][1] = __builtin_amdgcn_mfma_f32_32x32x16_bf16(a1, b1, acc[1][1], 0, 0, 0);
        }
        __syncthreads();
    }
#pragma unroll
    for (int at = 0; at < 2; ++at)
#pragma unroll
        for (int bt = 0; bt < 2; ++bt)
#pragma unroll
            for (int reg = 0; reg < 16; ++reg) {
                int lr = wm * 64 + at * 32 + (reg & 3) + 8 * (reg >> 2) + 4 * half;
                int u = ubase + wn * 64 + bt * 32 + l31;
                xvoT[(size_t)(b * DIM + ebase + lr) * SEQ + u] = f2bf(acc[at][bt][reg]);
            }
}

// ---------------- K6 v2: out = (P @ xvoT^T)*(1/den). 128q x 256e tile, BK=64, 32x32 ----
// 1-D grid 512, XCD swizzle: xcd=p&7 owns rows 16*xcd..+15 (all 4 e-tiles co-located
// on one XCD's L2). All 512 blocks co-resident (2/CU).
__global__ __launch_bounds__(512, 4) void k_pv(const unsigned short* __restrict__ P,
                                               const unsigned short* __restrict__ xvoT,
                                               const float* __restrict__ den_part,
                                               float* __restrict__ out) {
    __shared__ __align__(16) unsigned short a_lds[128 * 64];
    __shared__ __align__(16) unsigned short b_lds[256 * 64];
    __shared__ float rden[128];
    const int tid = threadIdx.x;
    const int w = tid >> 6, lane = tid & 63, l31 = lane & 31, half = lane >> 5;
    const int wm = w & 1, wn = w >> 1;

    const int p = blockIdx.x;
    const int xcd = p & 7, t = p >> 3;
    const int rowtile = xcd * 16 + (t >> 2);   // 0..127
    const int etile = t & 3;                   // 0..3
    const int rowbase = rowtile * 128;         // global q-row
    const int ebase = etile * 256;
    const int b = rowbase >> 12;

    if (tid < 128) {
        float s = 0.f;
#pragma unroll
        for (int i = 0; i < 8; ++i) s += den_part[(size_t)i * MTOT + rowbase + tid];
        rden[tid] = 1.0f / s;
    }

    f32x16 acc[2][2];
#pragma unroll
    for (int at = 0; at < 2; ++at)
#pragma unroll
        for (int bt = 0; bt < 2; ++bt)
#pragma unroll
            for (int i = 0; i < 16; ++i) acc[at][bt][i] = 0.f;

    const int sub = lane >> 3;
    const int g = (lane & 7) ^ (sub & 7);
    const int Ra = w * 16 + sub;
    const int Rb = w * 32 + sub;
    const unsigned short* Ap = P + (size_t)(rowbase + Ra) * SEQ + g * 8;
    const unsigned short* Bp = xvoT + (size_t)(b * DIM + ebase + Rb) * SEQ + g * 8;

    for (int k0 = 0; k0 < SEQ; k0 += 64) {
#pragma unroll
        for (int c = 0; c < 2; ++c)
            gl_lds16(Ap + (size_t)(c * 8) * SEQ + k0, &a_lds[(w * 16 + c * 8) * 64]);
#pragma unroll
        for (int c = 0; c < 4; ++c)
            gl_lds16(Bp + (size_t)(c * 8) * SEQ + k0, &b_lds[(w * 32 + c * 8) * 64]);
        __syncthreads();

        const int abase = (wm * 64 + l31) * 64;
        const int bbase = (wn * 64 + l31) * 64;
#pragma unroll
        for (int ks = 0; ks < 4; ++ks) {
            const int soff = ((ks * 2 + half) ^ (l31 & 7)) * 8;
            bf16x8 a0 = *(const bf16x8*)&a_lds[abase + soff];
            bf16x8 a1 = *(const bf16x8*)&a_lds[abase + 2048 + soff];
            bf16x8 b0 = *(const bf16x8*)&b_lds[bbase + soff];
            bf16x8 b1 = *(const bf16x8*)&b_lds[bbase + 2048 + soff];
            acc[0][0] = __builtin_amdgcn_mfma_f32_32x32x16_bf16(a0, b0, acc[0][0], 0, 0, 0);
            acc[0][1] = __builtin_amdgcn_mfma_f32_32x32x16_bf16(a0, b1, acc[0][1], 0, 0, 0);
            acc[1][0] = __builtin_amdgcn_mfma_f32_32x32x16_bf16(a1, b0, acc[1][0], 0, 0, 0);
            acc[1][1] = __builtin_amdgcn_mfma_f32_32x32x16_bf16(a1, b1, acc[1][1], 0, 0, 0);
        }
        __syncthreads();
    }
#pragma unroll
    for (int at = 0; at < 2; ++at)
#pragma unroll
        for (int bt = 0; bt < 2; ++bt)
#pragma unroll
            for (int reg = 0; reg < 16; ++reg) {
                int lr = wm * 64 + at * 32 + (reg & 3) + 8 * (reg >> 2) + 4 * half;
                int e = ebase + wn * 64 + bt * 32 + l31;
                out[(size_t)(rowbase + lr) * DIM + e] = acc[at][bt][reg] * rden[lr];
            }
}

extern "C" void kernel_launch(void* const* d_in, const int* in_sizes, int n_in,
                              void* d_out, int out_size, void* d_ws, size_t ws_size,
                              hipStream_t stream) {
    const float* x  = (const float*)d_in[0];
    const float* Q  = (const float*)d_in[1];
    const float* K  = (const float*)d_in[2];
    const float* VO = (const float*)d_in[3];
    float* out = (float*)d_out;

    char* ws = (char*)d_ws;
    unsigned short* wqk  = (unsigned short*)(ws + 0);           // 64x1024 bf16        128 KB
    unsigned short* vot  = (unsigned short*)(ws + 131072);      // 1024x1024 bf16        2 MB
    unsigned short* xqk  = (unsigned short*)(ws + 2228224);     // 16384x64 bf16         2 MB
    unsigned short* xbf  = (unsigned short*)(ws + 4325376);     // 16384x1024 bf16      32 MB
    unsigned short* xvoT = (unsigned short*)(ws + 37879808);    // 4x1024x4096 bf16     32 MB
    float*          denp = (float*)(ws + 71434240);             // 8x16384 fp32        512 KB
    unsigned short* P    = (unsigned short*)(ws + 71958528);    // 4x4096x4096 bf16    128 MB

    k_cvt_qk<<<256, 256, 0, stream>>>(Q, K, wqk);
    k_transpose_cvt<<<dim3(16, 16, 1), 256, 0, stream>>>(VO, vot, 1024, 1024);
    k_xbf<<<8192, 256, 0, stream>>>(x, xbf);
    k_proj<<<128, 256, 0, stream>>>(xbf, wqk, xqk);
    k_score<<<dim3(SEQ / 64, 8, BATCH), 256, 0, stream>>>(xqk, P, denp);
    k_xvo<<<dim3(16, 8, BATCH), 512, 0, stream>>>(vot, xbf, xvoT);
    k_pv<<<dim3(512, 1, 1), 512, 0, stream>>>(P, xvoT, denp, out);
}